// Round 5
// baseline (3688.483 us; speedup 1.0000x reference)
//
#include <hip/hip_runtime.h>

typedef __attribute__((ext_vector_type(8))) short short8;
typedef __attribute__((ext_vector_type(4))) float float4_t;
typedef __attribute__((ext_vector_type(2))) float float2_t;
typedef unsigned short u16;
typedef unsigned int u32;
typedef unsigned long long u64;

// B=256, T=256, IN=128, S=1024. Phases p=0..511: t=p>>1, stage=p&1.
// State words are (bf16<<16)|epoch — dword-atomic, self-validating; no barriers.

__device__ __forceinline__ u16 f2bf(float f) {
  u32 u = __builtin_bit_cast(u32, f);
  u += 0x7fffu + ((u >> 16) & 1u);          // RNE
  return (u16)(u >> 16);
}
__device__ __forceinline__ float bf2f(u16 h) {
  u32 u = ((u32)h) << 16;
  return __builtin_bit_cast(float, u);
}
__device__ __forceinline__ short8 cvt8(float4_t f0, float4_t f1) {
  short8 v;
  v[0]=(short)f2bf(f0[0]); v[1]=(short)f2bf(f0[1]); v[2]=(short)f2bf(f0[2]); v[3]=(short)f2bf(f0[3]);
  v[4]=(short)f2bf(f1[0]); v[5]=(short)f2bf(f1[1]); v[6]=(short)f2bf(f1[2]); v[7]=(short)f2bf(f1[3]);
  return v;
}

__global__ __launch_bounds__(256) void prep_w(const float* __restrict__ Wr,
                                              const float* __restrict__ Wr2,
                                              u16* __restrict__ W1b,
                                              u16* __restrict__ W2b) {
  const int i = blockIdx.x * 256 + threadIdx.x;   // 0 .. 1048575
  W1b[i] = f2bf(Wr[i]);
  W2b[i] = f2bf(Wr2[i]);
}

// ext GEMM: ebuf[t][b][n] = sum_k x[b][t][k]*Win[n][k] + bin[n], bf16 out.
// v2: WG = 64 rows x ALL 1024 cols (loop nt) -> x read once from HBM.
__global__ __launch_bounds__(256) void ext_gemm(const float* __restrict__ x,
                                                const float* __restrict__ Win,
                                                const float* __restrict__ bin,
                                                u16* __restrict__ ebuf) {
  const int mt = blockIdx.x;                      // 0..1023
  const int tid = threadIdx.x;
  const int wave = tid >> 6, lane = tid & 63, quad = lane >> 4, lm = lane & 15;
  const int m0 = (mt << 6) + (wave << 4);

  short8 a[4];
#pragma unroll
  for (int ks = 0; ks < 4; ++ks) {
    const float* p = x + (m0 + lm) * 128 + (ks * 32 + quad * 8);
    a[ks] = cvt8(*(const float4_t*)p, *(const float4_t*)(p + 4));
  }
  for (int nt = 0; nt < 16; ++nt) {
    const int n0 = nt << 6;
    short8 bfr[4][4];
#pragma unroll
    for (int nsub = 0; nsub < 4; ++nsub)
#pragma unroll
      for (int ks = 0; ks < 4; ++ks) {
        const float* p = Win + (n0 + (nsub << 4) + lm) * 128 + (ks * 32 + quad * 8);
        bfr[nsub][ks] = cvt8(*(const float4_t*)p, *(const float4_t*)(p + 4));
      }
    float4_t acc[4] = { {0,0,0,0},{0,0,0,0},{0,0,0,0},{0,0,0,0} };
#pragma unroll
    for (int ks = 0; ks < 4; ++ks)
#pragma unroll
      for (int nsub = 0; nsub < 4; ++nsub)
        acc[nsub] = __builtin_amdgcn_mfma_f32_16x16x32_bf16(a[ks], bfr[nsub][ks], acc[nsub], 0, 0, 0);
#pragma unroll
    for (int nsub = 0; nsub < 4; ++nsub) {
      const int n = n0 + (nsub << 4) + lm;
      const float bv = bin[n];
#pragma unroll
      for (int r = 0; r < 4; ++r) {
        const int m = m0 + (quad << 2) + r;
        const int b = m >> 8, t = m & 255;
        ebuf[(((t << 8) | b) << 10) + n] = f2bf(acc[nsub][r] + bv);
      }
    }
  }
}

// Persistent recurrence. 256 WGs x 512 thr. WG=(mt:16 rows, ns:64 cols). Waves 0-3: W1
// k-quarters, 4-7: W2. NO barriers/counters: consumers spin on tagged state words
// (epoch==p); producers just store (value|epoch) — dword atomicity self-validates.
__global__ __launch_bounds__(512, 2) void rnn_persistent(
    const u16* __restrict__ ebuf, u32* __restrict__ tbuf0, u32* __restrict__ tbuf1,
    const u16* __restrict__ W1b, const u16* __restrict__ W2b,
    const float* __restrict__ b1, const float* __restrict__ b2,
    float* __restrict__ fbuf) {
  __shared__ __align__(16) float Pt[2][4][16][68];   // ping-pong k-split partials

  const int tid = threadIdx.x;
  const int wave = tid >> 6, lane = tid & 63, quad = lane >> 4, lm = lane & 15;
  const int mt = blockIdx.x >> 4, ns = blockIdx.x & 15;
  const int n0 = ns << 6;
  const int mat = wave >> 2, q = wave & 3;

  short8 wfrag[4][8];   // persistent B fragments
  {
    const u16* Wm = mat ? W2b : W1b;
#pragma unroll
    for (int nsub = 0; nsub < 4; ++nsub)
#pragma unroll
      for (int ks = 0; ks < 8; ++ks)
        wfrag[nsub][ks] = __builtin_bit_cast(short8,
            *(const uint4*)(Wm + ((n0 + (nsub << 4) + lm) << 10) + (q << 8) + (ks << 5) + (quad << 3)));
  }

  const int me = tid >> 5;               // epilogue row 0..15
  const int nc = (tid & 31) << 1;        // epilogue col base (2 cols)

  for (int p = 0; p < 512; ++p) {
    const int t = p >> 1, st = p & 1;

    u32 e2 = 0;   // e(t+1) prefetch for stage-2 epilogue (plain cached load)
    if (st && t < 255)
      e2 = *(const u32*)(ebuf + ((((t + 1) << 8) + (mt << 4) + me) << 10) + n0 + nc);

    if (mat == st) {    // active waves: acquire A-fragments, MFMA
      short8 afr[8];
      if (p == 0) {     // t=0 state = ebuf[0] (plain bf16, pre-kernel data)
        const u16* rb = ebuf + (((mt << 4) + lm) << 10) + (q << 8) + (quad << 3);
#pragma unroll
        for (int ks = 0; ks < 8; ++ks)
          afr[ks] = *(const short8*)(rb + (ks << 5));
      } else {
        const u32* rb = (st ? tbuf1 : tbuf0) + (((mt << 4) + lm) << 10) + (q << 8) + (quad << 3);
        const u32 exp = (u32)p;
        u64 raw[8][4];
        for (;;) {      // poll-load: data IS the flag
#pragma unroll
          for (int ks = 0; ks < 8; ++ks)
#pragma unroll
            for (int j = 0; j < 4; ++j)
              raw[ks][j] = __hip_atomic_load((const u64*)(rb + (ks << 5) + (j << 1)),
                                             __ATOMIC_RELAXED, __HIP_MEMORY_SCOPE_AGENT);
          u32 bad = 0;
#pragma unroll
          for (int ks = 0; ks < 8; ++ks)
#pragma unroll
            for (int j = 0; j < 4; ++j) {
              const u32 lo = (u32)raw[ks][j], hi = (u32)(raw[ks][j] >> 32);
              bad |= ((lo ^ exp) | (hi ^ exp)) & 0xffffu;
            }
          if (__all(bad == 0)) break;
          __builtin_amdgcn_s_sleep(1);
        }
#pragma unroll
        for (int ks = 0; ks < 8; ++ks) {
          uint4 pk;
          const u32 l0 = (u32)raw[ks][0], h0 = (u32)(raw[ks][0] >> 32);
          const u32 l1 = (u32)raw[ks][1], h1 = (u32)(raw[ks][1] >> 32);
          const u32 l2 = (u32)raw[ks][2], h2 = (u32)(raw[ks][2] >> 32);
          const u32 l3 = (u32)raw[ks][3], h3 = (u32)(raw[ks][3] >> 32);
          pk.x = (l0 >> 16) | (h0 & 0xffff0000u);
          pk.y = (l1 >> 16) | (h1 & 0xffff0000u);
          pk.z = (l2 >> 16) | (h2 & 0xffff0000u);
          pk.w = (l3 >> 16) | (h3 & 0xffff0000u);
          afr[ks] = __builtin_bit_cast(short8, pk);
        }
      }
      float4_t acc[4] = { {0,0,0,0},{0,0,0,0},{0,0,0,0},{0,0,0,0} };
#pragma unroll
      for (int ks = 0; ks < 8; ++ks)
#pragma unroll
        for (int nsub = 0; nsub < 4; ++nsub)
          acc[nsub] = __builtin_amdgcn_mfma_f32_16x16x32_bf16(afr[ks], wfrag[nsub][ks], acc[nsub], 0, 0, 0);
#pragma unroll
      for (int nsub = 0; nsub < 4; ++nsub)
#pragma unroll
        for (int r = 0; r < 4; ++r)
          Pt[p & 1][q][(quad << 2) + r][(nsub << 4) + lm] = acc[nsub][r];
    }
    __syncthreads();

    // epilogue (all 8 waves): reduce k-split, bias, relu, (+e), tagged store
    {
      const float2_t p0 = *(const float2_t*)&Pt[p & 1][0][me][nc];
      const float2_t p1 = *(const float2_t*)&Pt[p & 1][1][me][nc];
      const float2_t p2 = *(const float2_t*)&Pt[p & 1][2][me][nc];
      const float2_t p3 = *(const float2_t*)&Pt[p & 1][3][me][nc];
      const float* bv = st ? b2 : b1;
      const float2_t bias = *(const float2_t*)(bv + n0 + nc);
      float2_t s = p0 + p1 + p2 + p3 + bias;
      s[0] = s[0] > 0.f ? s[0] : 0.f;
      s[1] = s[1] > 0.f ? s[1] : 0.f;
      const int gr = (mt << 4) + me;
      if (p == 511) {
        *(float2_t*)(fbuf + (gr << 10) + n0 + nc) = s;   // final state (kernel-end flush)
      } else {
        if (st) { s[0] += bf2f((u16)(e2 & 0xffffu)); s[1] += bf2f((u16)(e2 >> 16)); }
        const u32 ep = (u32)(p + 1);
        const u64 w = (u64)(((u32)f2bf(s[0]) << 16) | ep)
                    | ((u64)(((u32)f2bf(s[1]) << 16) | ep) << 32);
        u32* dst = (st ? tbuf0 : tbuf1) + (gr << 10) + n0 + nc;
        __hip_atomic_store((u64*)dst, w, __ATOMIC_RELAXED, __HIP_MEMORY_SCOPE_AGENT);
      }
    }
  }
}

__global__ __launch_bounds__(256) void bcast(const float* __restrict__ fbuf,
                                             float* __restrict__ out) {
  const int idx4 = blockIdx.x * 256 + threadIdx.x;   // 0..16777215 float4s
  const int b = idx4 >> 16;
  const int s4 = idx4 & 255;
  const float4_t v = *(const float4_t*)(fbuf + (b << 10) + (s4 << 2));
  *(float4_t*)(out + ((size_t)idx4 << 2)) = v;
}

extern "C" void kernel_launch(void* const* d_in, const int* in_sizes, int n_in,
                              void* d_out, int out_size, void* d_ws, size_t ws_size,
                              hipStream_t stream) {
  const float* x     = (const float*)d_in[0];
  const float* Win   = (const float*)d_in[1];
  const float* bin   = (const float*)d_in[2];
  const float* Wrec  = (const float*)d_in[3];
  const float* brec  = (const float*)d_in[4];
  const float* Wrec2 = (const float*)d_in[5];
  const float* brec2 = (const float*)d_in[6];
  float* out = (float*)d_out;

  char* ws = (char*)d_ws;
  u16* W1b   = (u16*)(ws);                 // 2 MB
  u16* W2b   = (u16*)(ws + (2u << 20));    // 2 MB
  u32* tbuf0 = (u32*)(ws + (4u << 20));    // 1 MB tagged state (stage2 out)
  u32* tbuf1 = (u32*)(ws + (5u << 20));    // 1 MB tagged state (stage1 out)
  float* fbuf = (float*)(ws + (6u << 20)); // 1 MB
  u16* ebuf = (u16*)d_out;  // 128 MB scratch inside out (268 MB); dead before bcast
  // No init kernel: 0xAA poison (epoch 0xAAAA) never matches expected epochs 1..512.

  prep_w<<<4096, 256, 0, stream>>>(Wrec, Wrec2, W1b, W2b);
  ext_gemm<<<1024, 256, 0, stream>>>(x, Win, bin, ebuf);

  void* args[] = { (void*)&ebuf, (void*)&tbuf0, (void*)&tbuf1, (void*)&W1b, (void*)&W2b,
                   (void*)&brec, (void*)&brec2, (void*)&fbuf };
  (void)hipLaunchCooperativeKernel(reinterpret_cast<void*>(rnn_persistent),
                                   dim3(256), dim3(512), args, 0, stream);

  bcast<<<65536, 256, 0, stream>>>(fbuf, out);
}